// Round 7
// baseline (150.316 us; speedup 1.0000x reference)
//
#include <hip/hip_runtime.h>
#include <stdint.h>

#define KK 5
#define TT 512

// ---- cross-lane helpers (8-lane groups; 8 | 32 so groups never straddle the
// ds_swizzle 32-lane boundary) ----
template<int P> __device__ __forceinline__ float swzf(float v) {
  return __int_as_float(__builtin_amdgcn_ds_swizzle(__float_as_int(v), P));
}
template<int P> __device__ __forceinline__ int swzi(int v) {
  return __builtin_amdgcn_ds_swizzle(v, P);
}
// broadcast lane (group*8 + i): offset = (i<<5) | 0x18
#define BC0 0x018
#define BC1 0x038
#define BC2 0x058
#define BC3 0x078
#define BC4 0x098
// xor-butterfly within 8-lane group: offset = (m<<10) | 0x1F
#define X1 0x041F
#define X2 0x081F
#define X4 0x101F

__device__ __forceinline__ float sel5f(float v0,float v1,float v2,float v3,float v4,int ct){
  float u=v0; u=(ct==1)?v1:u; u=(ct==2)?v2:u; u=(ct==3)?v3:u; u=(ct==4)?v4:u; return u;
}
__device__ __forceinline__ uint32_t sel5u(uint32_t w0,uint32_t w1,uint32_t w2,uint32_t w3,uint32_t w4,int ct){
  uint32_t u=w0; u=(ct==1)?w1:u; u=(ct==2)?w2:u; u=(ct==3)?w3:u; u=(ct==4)?w4:u; return u;
}
#define MAX5(a,b,c,d,e) fmaxf(fmaxf(fmaxf(a,b),fmaxf(c,d)),e)
__device__ __forceinline__ int amax5(float s0,float s1,float s2,float s3,float s4,float bm){
  int bi=4; bi=(s3==bm)?3:bi; bi=(s2==bm)?2:bi; bi=(s1==bm)?1:bi; bi=(s0==bm)?0:bi; return bi;
}

// One chunk = 4 pairs (8 time steps). Per pair h: t1=2h (full 5-vector pot),
// t2=2h+1 (own-column pot). t1 even -> 20*t1 B is 8-aligned -> float2 legal.
struct PB { float2 q0[4]; float2 q1[4]; float e[4]; float p2[4]; };

__device__ __forceinline__ void loadPB(PB& d, const float* __restrict__ prow,
                                       const float* __restrict__ colp, int c, int H) {
#pragma unroll
  for (int s = 0; s < 4; ++s) {
    const int h = min(4 * c + 1 + s, H);
    const float* base = prow + (2 * h) * KK;
    d.q0[s] = *(const float2*)(base);
    d.q1[s] = *(const float2*)(base + 2);
    d.e[s]  = base[4];
    d.p2[s] = colp[(2 * h + 1) * KK];
  }
}

// ---------------- Viterbi: one chunk of 4 composed pairs ----------------
__device__ __forceinline__ void vit_chunk(const PB& U, int c, int H, int len,
    const float (&trS)[KK][KK], const float (&trc)[KK],
    float& a, float& a_fin, uint32_t& bits,
    int g, int r, int jj, uint32_t* __restrict__ s_bits) {
#pragma unroll
  for (int s = 0; s < 4; ++s) {
    const int h = 4 * c + 1 + s;
    if (h <= H) {                       // wave-uniform guard
      const int t1 = 2 * h, t2 = 2 * h + 1;
      const float p10 = U.q0[s].x, p11 = U.q0[s].y, p12 = U.q1[s].x,
                  p13 = U.q1[s].y, p14 = U.e[s];
      const float av0 = swzf<BC0>(a), av1 = swzf<BC1>(a), av2 = swzf<BC2>(a),
                  av3 = swzf<BC3>(a), av4 = swzf<BC4>(a);
      // bp at t1 (own column jj) -- exact reference op order
      const float c0 = av0 + trc[0], c1 = av1 + trc[1], c2 = av2 + trc[2],
                  c3 = av3 + trc[3], c4 = av4 + trc[4];
      const float bm1 = MAX5(c0, c1, c2, c3, c4);
      const int bi1 = amax5(c0, c1, c2, c3, c4, bm1);
      // full intermediate alpha_{t1}[k] (wave-uniform trans table -> SGPR)
      const float m0 = MAX5(av0+trS[0][0], av1+trS[1][0], av2+trS[2][0], av3+trS[3][0], av4+trS[4][0]);
      const float m1 = MAX5(av0+trS[0][1], av1+trS[1][1], av2+trS[2][1], av3+trS[3][1], av4+trS[4][1]);
      const float m2 = MAX5(av0+trS[0][2], av1+trS[1][2], av2+trS[2][2], av3+trS[3][2], av4+trS[4][2]);
      const float m3 = MAX5(av0+trS[0][3], av1+trS[1][3], av2+trS[2][3], av3+trS[3][3], av4+trS[4][3]);
      const float m4 = MAX5(av0+trS[0][4], av1+trS[1][4], av2+trS[2][4], av3+trS[3][4], av4+trS[4][4]);
      const float al0 = m0 + p10, al1 = m1 + p11, al2 = m2 + p12,
                  al3 = m3 + p13, al4 = m4 + p14;
      // step t2 (own column)
      const float u0 = al0 + trc[0], u1 = al1 + trc[1], u2 = al2 + trc[2],
                  u3 = al3 + trc[3], u4 = al4 + trc[4];
      const float bm2 = MAX5(u0, u1, u2, u3, u4);
      const int bi2 = amax5(u0, u1, u2, u3, u4, bm2);
      const float anew = bm2 + U.p2[s];
      // off-chain captures of alpha at len-1
      a_fin = (t1 == len - 1) ? sel5f(al0, al1, al2, al3, al4, jj) : a_fin;
      a = anew;
      a_fin = (t2 == len - 1) ? a : a_fin;
      // bits: field for transition into t at 3*((t-1)&7), block (t-1)>>3
      bits |= (uint32_t)bi1 << (3 * ((t1 - 1) & 7));
      if (s == 3) {                      // (t1-1)&7 == 7 here; block index == c
        if (r < 5) s_bits[g * 321 + c * 5 + jj] = bits;
        bits = 0;
      }
      bits |= (uint32_t)bi2 << (3 * ((t2 - 1) & 7));
    }
  }
}

// ---------------- forward: one chunk of 4 composed pairs ----------------
__device__ __forceinline__ void fwd_chunk(const PB& U, int c, int H, int len,
    const float (&WS)[KK][KK], const float (&Wc)[KK],
    float& p, float& Cacc, float& p_fin, float& C_fin, int jj) {
#pragma unroll
  for (int s = 0; s < 4; ++s) {
    const int h = 4 * c + 1 + s;
    if (h <= H) {
      const int t1 = 2 * h, t2 = 2 * h + 1;
      const float pv0 = swzf<BC0>(p), pv1 = swzf<BC1>(p), pv2 = swzf<BC2>(p),
                  pv3 = swzf<BC3>(p), pv4 = swzf<BC4>(p);
      const float E10 = __expf(U.q0[s].x), E11 = __expf(U.q0[s].y),
                  E12 = __expf(U.q1[s].x), E13 = __expf(U.q1[s].y),
                  E14 = __expf(U.e[s]);
      const float P0 = fmaf(pv4,WS[4][0],fmaf(pv3,WS[3][0],fmaf(pv2,WS[2][0],fmaf(pv1,WS[1][0],pv0*WS[0][0])))) * E10;
      const float P1 = fmaf(pv4,WS[4][1],fmaf(pv3,WS[3][1],fmaf(pv2,WS[2][1],fmaf(pv1,WS[1][1],pv0*WS[0][1])))) * E11;
      const float P2 = fmaf(pv4,WS[4][2],fmaf(pv3,WS[3][2],fmaf(pv2,WS[2][2],fmaf(pv1,WS[1][2],pv0*WS[0][2])))) * E12;
      const float P3 = fmaf(pv4,WS[4][3],fmaf(pv3,WS[3][3],fmaf(pv2,WS[2][3],fmaf(pv1,WS[1][3],pv0*WS[0][3])))) * E13;
      const float P4 = fmaf(pv4,WS[4][4],fmaf(pv3,WS[3][4],fmaf(pv2,WS[2][4],fmaf(pv1,WS[1][4],pv0*WS[0][4])))) * E14;
      const float m = MAX5(P0, P1, P2, P3, P4);   // uniform across group
      const float acc = fmaf(P4,Wc[4],fmaf(P3,Wc[3],fmaf(P2,Wc[2],fmaf(P1,Wc[1],P0*Wc[0]))));
      const float pnew = acc * __expf(U.p2[s]);
      // captures (pre-renorm; Cacc not yet bumped)
      p_fin = (t1 == len - 1) ? sel5f(P0, P1, P2, P3, P4, jj) : p_fin;
      C_fin = (t1 == len - 1) ? Cacc : C_fin;
      p_fin = (t2 == len - 1) ? pnew : p_fin;
      C_fin = (t2 == len - 1) ? Cacc : C_fin;
      // renorm once per pair (uniform scale; exact bookkeeping)
      p = pnew * (1.0f / m);
      Cacc += __logf(m);
    }
  }
}

// ---------------------------------------------------------------------------
// grid: 2*(B/8) blocks x 64 threads (1 wave). 8 batches/wave, 8 lanes/batch
// (5 compute tags). role via (blockIdx>>3)&1; blocks u and u+8 share batches
// and XCD. No barriers; backtrace/decode fully post-scan.
// ---------------------------------------------------------------------------
__launch_bounds__(64)
__global__ void crf_kernel(const float* __restrict__ pot,
                           const float* __restrict__ trans,
                           const int* __restrict__ lens,
                           const int* __restrict__ tags,
                           float* __restrict__ out,
                           int B, int T) {
  __shared__ uint32_t s_bits[8 * 321];    // [g][k][j] at g*321 + k*5 + j
  __shared__ uint32_t s_chosen[8 * 65];   // packed decoded tags per 8-step block
  const int lane = threadIdx.x;
  const int g = lane >> 3, r = lane & 7;
  const int jj = (r < 5) ? r : 4;
  const unsigned u = blockIdx.x;
  const int role = (u >> 3) & 1;
  const int idx = (int)((u & 7u) | ((u >> 4) << 3));
  const int b = idx * 8 + g;
  const int len = lens[b];
  const float* __restrict__ prow = pot + (size_t)b * (T * KK);
  const float* __restrict__ colp = prow + jj;

  int ml = len;
  ml = max(ml, __shfl_xor(ml, 8));
  ml = max(ml, __shfl_xor(ml, 16));
  ml = max(ml, __shfl_xor(ml, 32));
  const int H = (ml >= 3) ? ((ml - 1) >> 1) : 0;   // pairs h=1..H cover t=2..2H+1
  const int NC = (H + 3) >> 2;                     // chunks of 4 pairs
  const bool doLone = (ml >= 2);                   // lone step t=1

  if (role == 0) {
    // ========================= Viterbi =========================
    PB A, Bb;
    if (NC > 0) loadPB(A, prow, colp, 0, H);
    if (NC > 1) loadPB(Bb, prow, colp, 1, H);
    float trS[KK][KK], trc[KK];
#pragma unroll
    for (int i = 0; i < KK; ++i) {
#pragma unroll
      for (int k = 0; k < KK; ++k) trS[i][k] = trans[i * KK + k];  // uniform -> SGPR
      trc[i] = trans[i * KK + jj];
    }
    float a = (r < 5) ? prow[jj] : -3.0e38f;
    float a_fin = a;                       // covers len==1
    uint32_t bits = 0;
    if (doLone) {
      const float p1own = colp[KK];
      const float av0 = swzf<BC0>(a), av1 = swzf<BC1>(a), av2 = swzf<BC2>(a),
                  av3 = swzf<BC3>(a), av4 = swzf<BC4>(a);
      const float c0 = av0 + trc[0], c1 = av1 + trc[1], c2 = av2 + trc[2],
                  c3 = av3 + trc[3], c4 = av4 + trc[4];
      const float bm = MAX5(c0, c1, c2, c3, c4);
      const int bi = amax5(c0, c1, c2, c3, c4, bm);
      a = bm + p1own;
      a_fin = (len == 2) ? a : a_fin;
      bits = (uint32_t)bi;                 // field s=0, block 0
    }
    int c = 0;
    while (c < NC) {
      vit_chunk(A, c, H, len, trS, trc, a, a_fin, bits, g, r, jj, s_bits);
      if (c + 2 < NC) loadPB(A, prow, colp, c + 2, H);
      ++c;
      if (c >= NC) break;
      vit_chunk(Bb, c, H, len, trS, trc, a, a_fin, bits, g, r, jj, s_bits);
      if (c + 2 < NC) loadPB(Bb, prow, colp, c + 2, H);
      ++c;
    }
    if (r < 5) s_bits[g * 321 + ((2 * H) >> 3) * 5 + jj] = bits;  // final flush

    // final argmax (first-max) over lanes r<5
    float bm = a_fin;
    bm = fmaxf(bm, swzf<X1>(bm));
    bm = fmaxf(bm, swzf<X2>(bm));
    bm = fmaxf(bm, swzf<X4>(bm));
    int cand = (r < 5 && a_fin == bm) ? r : 7;
    cand = min(cand, swzi<X1>(cand));
    cand = min(cand, swzi<X2>(cand));
    cand = min(cand, swzi<X4>(cand));
    const int last = cand;

    // ============ post-scan backtrace: lane r==0 per group ============
    if (r == 0) {
      int tag = last;
      uint32_t acc = (uint32_t)last << (3 * ((len - 1) & 7));
      int kcur = (len - 1) >> 3;
      const uint32_t* __restrict__ bb = s_bits + g * 321;
      int kb = (len - 2) >> 3;               // len==1 -> -1, loop skipped
      uint32_t w0 = 0, w1 = 0, w2 = 0, w3 = 0, w4 = 0;
      if (kb >= 0) {
        w0 = bb[kb * 5 + 0]; w1 = bb[kb * 5 + 1]; w2 = bb[kb * 5 + 2];
        w3 = bb[kb * 5 + 3]; w4 = bb[kb * 5 + 4];
      }
      for (; kb >= 0; --kb) {
        uint32_t n0 = 0, n1 = 0, n2 = 0, n3 = 0, n4 = 0;
        if (kb > 0) {
          n0 = bb[(kb - 1) * 5 + 0]; n1 = bb[(kb - 1) * 5 + 1];
          n2 = bb[(kb - 1) * 5 + 2]; n3 = bb[(kb - 1) * 5 + 3];
          n4 = bb[(kb - 1) * 5 + 4];
        }
#pragma unroll
        for (int s = 7; s >= 0; --s) {
          const int t = kb * 8 + s + 1;      // transition into t; position t-1
          if (t <= len - 1) {
            const uint32_t w = sel5u(w0, w1, w2, w3, w4, tag);
            const int prev = (int)((w >> (3 * s)) & 7u);
            if (kb != kcur) { s_chosen[g * 65 + kcur] = acc; acc = 0; kcur = kb; }
            acc |= (uint32_t)prev << (3 * s);
            tag = prev;
          }
        }
        w0 = n0; w1 = n1; w2 = n2; w3 = n3; w4 = n4;
      }
      s_chosen[g * 65 + kcur] = acc;
    }

    // ============ coalesced decoded write (all lanes) ============
    float* __restrict__ orow = out + (size_t)b * T;
#pragma unroll
    for (int kk = 0; kk < 8; ++kk) {
      const int k2 = kk * 8 + r;
      const uint32_t w = s_chosen[g * 65 + k2];
      const int base = k2 * 8;
      float f[8];
#pragma unroll
      for (int pI = 0; pI < 8; ++pI)
        f[pI] = (base + pI < len) ? (float)((w >> (3 * pI)) & 7u) : 0.0f;
      *(float4*)(orow + base)     = make_float4(f[0], f[1], f[2], f[3]);
      *(float4*)(orow + base + 4) = make_float4(f[4], f[5], f[6], f[7]);
    }

  } else {
    // ==================== forward + score ====================
    PB A, Bb;
    if (NC > 0) loadPB(A, prow, colp, 0, H);
    if (NC > 1) loadPB(Bb, prow, colp, 1, H);

    const float trv = trans[min(lane, 24)];   // distributed 5x5 table
    // ---- score prologue: lane r sums t in [r*64, r*64+64) of its batch ----
    const int* __restrict__ tgrow = tags + (size_t)b * T;
    float sc = 0.0f;
    {
      const int t0 = r * 64;
      int ptag = (t0 == 0) ? 0 : tgrow[t0 - 1];
#pragma unroll 2
      for (int q = 0; q < 16; ++q) {
        const int4 tq = *(const int4*)(tgrow + t0 + q * 4);
#pragma unroll
        for (int m = 0; m < 4; ++m) {
          const int t = t0 + q * 4 + m;
          const int ct = (m == 0) ? tq.x : (m == 1) ? tq.y : (m == 2) ? tq.z : tq.w;
          const float uadd = prow[t * KK + ct];
          const float badd = __int_as_float(__builtin_amdgcn_ds_bpermute(
              (ptag * KK + ct) << 2, __float_as_int(trv)));
          const float contrib = uadd + ((t >= 1) ? badd : 0.0f);
          sc += (t < len) ? contrib : 0.0f;
          ptag = ct;
        }
      }
    }
    sc += swzf<X1>(sc);
    sc += swzf<X2>(sc);
    sc += swzf<X4>(sc);                 // group total

    float WS[KK][KK], Wc[KK];
#pragma unroll
    for (int i = 0; i < KK; ++i) {
#pragma unroll
      for (int k = 0; k < KK; ++k) WS[i][k] = __expf(trans[i * KK + k]);
      Wc[i] = __expf(trans[i * KK + jj]);
    }
    float p = (r < 5) ? __expf(prow[jj]) : 0.0f;
    float Cacc = 0.0f;
    float p_fin = p, C_fin = 0.0f;      // covers len==1
    if (doLone) {
      const float pv0 = swzf<BC0>(p), pv1 = swzf<BC1>(p), pv2 = swzf<BC2>(p),
                  pv3 = swzf<BC3>(p), pv4 = swzf<BC4>(p);
      const float acc = fmaf(pv4,Wc[4],fmaf(pv3,Wc[3],fmaf(pv2,Wc[2],fmaf(pv1,Wc[1],pv0*Wc[0]))));
      p = acc * __expf(colp[KK]);
      p_fin = (len == 2) ? p : p_fin;   // C_fin stays 0
    }
    int c = 0;
    while (c < NC) {
      fwd_chunk(A, c, H, len, WS, Wc, p, Cacc, p_fin, C_fin, jj);
      if (c + 2 < NC) loadPB(A, prow, colp, c + 2, H);
      ++c;
      if (c >= NC) break;
      fwd_chunk(Bb, c, H, len, WS, Wc, p, Cacc, p_fin, C_fin, jj);
      if (c + 2 < NC) loadPB(Bb, prow, colp, c + 2, H);
      ++c;
    }
    float ps = (r < 5) ? p_fin : 0.0f;
    ps += swzf<X1>(ps);
    ps += swzf<X2>(ps);
    ps += swzf<X4>(ps);
    const float logZ = C_fin + __logf(ps);
    if (r == 0) out[(size_t)B * T + b] = sc - logZ;
  }
}

// ---------------------------------------------------------------------------
extern "C" void kernel_launch(void* const* d_in, const int* in_sizes, int n_in,
                              void* d_out, int out_size, void* d_ws, size_t ws_size,
                              hipStream_t stream) {
  const float* pot   = (const float*)d_in[0];
  const float* trans = (const float*)d_in[1];
  const int*   lens  = (const int*)d_in[2];
  const int*   tags  = (const int*)d_in[3];
  float* out = (float*)d_out;

  const int B = in_sizes[2];
  const int T = in_sizes[3] / B;   // 512

  const int nblocks = 2 * (B / 8);  // 2048
  crf_kernel<<<nblocks, 64, 0, stream>>>(pot, trans, lens, tags, out, B, T);
}